// Round 10
// baseline (337.642 us; speedup 1.0000x reference)
//
#include <hip/hip_runtime.h>
#include <hip/hip_fp16.h>

// Volume rotate + trilinear resample + projection along axis 2.
// Round-8 (2nd resubmit; two GPU-acquisition timeouts, experiment unmeasured):
// fp16 4-corner pack (134 MB, L3-resident) -> 2 gathers/sample,
// 4x4x4 compact wave sample-bricks (round-6/7), PLUS:
//  - main loop VALU trim: pixel-space fused ray constants (continuity-safe),
//    v_fract + trunc-cvt for floor/frac, incremental exact kf, idx+(dz<<16).
//  - pack kernel: LDS row-sharing (1.06x reads) + nontemporal stores.

#define NN 256

typedef unsigned uv4 __attribute__((ext_vector_type(4)));

// ---------------- helpers ----------------

__device__ __forceinline__ unsigned pack2h(float lo, float hi) {
    __half2 h = __floats2half2_rn(lo, hi);
    return *reinterpret_cast<unsigned*>(&h);
}

__device__ __forceinline__ float2 unpack2h(unsigned u) {
    __half2 h = *reinterpret_cast<__half2*>(&u);
    return __half22float2(h);
}

// ---------------- pack kernel (LDS row-shared, nt stores) ----------------
// v4h[t], t=(z<<16)|(y<<8)|x : uint2{ lo = (V[z,y,x],V[z,y,x1]) fp16x2,
//                                     hi = (V[z,y1,x],V[z,y1,x1]) fp16x2 }
// Block = one z-plane 16-row stripe: loads 17 rows into LDS once, emits 16.

__global__ __launch_bounds__(256) void pack4h_kernel(
    const float* __restrict__ vol, uint2* __restrict__ v4)
{
    __shared__ float rows[17][256];

    const int z = blockIdx.x >> 4;
    const int ys = (blockIdx.x & 15) << 4;
    const int tid = threadIdx.x;
    const int w = tid >> 6;        // wave 0..3
    const int l = tid & 63;        // lane

    // load rows ys..ys+16 (clamped) into LDS, one row per wave per iter
    for (int r = w; r < 17; r += 4) {
        const int y = min(ys + r, NN - 1);
        const float4 v = *reinterpret_cast<const float4*>(
            vol + ((z << 16) | (y << 8) | (l << 2)));
        *reinterpret_cast<float4*>(&rows[r][l << 2]) = v;
    }
    __syncthreads();

    // emit 16 rows x 64 x4-groups = 1024 tasks, 4 per thread
    for (int task = tid; task < 1024; task += 256) {
        const int ry = task >> 6;
        const int x4 = (task & 63) << 2;

        const float4 p0 = *reinterpret_cast<const float4*>(&rows[ry][x4]);
        const float4 p1 = *reinterpret_cast<const float4*>(&rows[ry + 1][x4]);
        const float n0 = (x4 == 252) ? p0.w : rows[ry][x4 + 4];
        const float n1 = (x4 == 252) ? p1.w : rows[ry + 1][x4 + 4];

        uv4 lo, hi;
        lo.x = pack2h(p0.x, p0.y);  lo.y = pack2h(p1.x, p1.y);   // x4+0
        lo.z = pack2h(p0.y, p0.z);  lo.w = pack2h(p1.y, p1.z);   // x4+1
        hi.x = pack2h(p0.z, p0.w);  hi.y = pack2h(p1.z, p1.w);   // x4+2
        hi.z = pack2h(p0.w, n0);    hi.w = pack2h(p1.w, n1);     // x4+3

        uv4* dst = reinterpret_cast<uv4*>(
            v4 + (((size_t)z << 16) | ((ys + ry) << 8) | x4));
        __builtin_nontemporal_store(lo, dst);
        __builtin_nontemporal_store(hi, dst + 1);
    }
}

// ---------------- geometry ----------------
// Pixel-space ray constants. Derivation (continuity-safe):
//   raw P = gk*r_2 + base; ref: pix = (clip(P/128,-1,1)+1)*127.5
//   /128 fold is bit-exact (power-of-2 scale commutes with rounding).
//   map is monotonic -> clamp after map == map of clamp; fused fma differs
//   by ~1 ulp in pixel space; trilinear interp is C0 -> output shift ~1e-3.

struct RayCtx {
    float bPx, bPy, bPz;    // pixel-space base
    float dPx, dPy, dPz;    // pixel-space k-direction
};

__device__ __forceinline__ RayCtx make_ray(const float* __restrict__ quats,
                                           int b, int i, int j)
{
    const float q0 = quats[b * 4 + 0];
    const float q1 = quats[b * 4 + 1];
    const float q2 = quats[b * 4 + 2];
    const float q3 = quats[b * 4 + 3];
    const float nrm = sqrtf(q0 * q0 + q1 * q1 + q2 * q2 + q3 * q3);
    const float qw = q0 / nrm, qx = q1 / nrm, qy = q2 / nrm, qz = q3 / nrm;

    const float r00 = 1.0f - 2.0f * (qy * qy + qz * qz);
    const float r01 = 2.0f * (qx * qy - qz * qw);
    const float r02 = 2.0f * (qx * qz + qy * qw);
    const float r10 = 2.0f * (qx * qy + qz * qw);
    const float r11 = 1.0f - 2.0f * (qx * qx + qz * qz);
    const float r12 = 2.0f * (qy * qz - qx * qw);
    const float r20 = 2.0f * (qx * qz - qy * qw);
    const float r21 = 2.0f * (qy * qz + qx * qw);
    const float r22 = 1.0f - 2.0f * (qx * qx + qy * qy);

    const float gi = (float)i - 128.0f;
    const float gj = (float)j - 128.0f;

    const float bx = gi * r00 + gj * r01;
    const float by = gi * r10 + gj * r11;
    const float bz = gi * r20 + gj * r21;

    const float K = 127.5f / 128.0f;   // 0.99609375, exact fp32
    RayCtx c;
    c.dPx = r02 * K;  c.dPy = r12 * K;  c.dPz = r22 * K;
    c.bPx = bx * K + 127.5f;
    c.bPy = by * K + 127.5f;
    c.bPz = bz * K + 127.5f;
    return c;
}

// ---------------- main kernel: 4x4x4 lane bricks, 2 gathers/sample ----------
// lane l: di = l&3 (i), dj = (l>>2)&3 (j), dk = l>>4 (k residue).
// Lane partial: sum over k = 4t+dk, t=0..63. Fold dk via shfl_xor(16|32).

__global__ __launch_bounds__(256) void rotproj4h_kernel(
    const uint2* __restrict__ v4,
    const float* __restrict__ quats,
    float* __restrict__ out)
{
    const int tid = threadIdx.x;
    const int w = tid >> 6;
    const int l = tid & 63;
    const int di = l & 3;
    const int dj = (l >> 2) & 3;
    const int dk = l >> 4;

    const int b = blockIdx.z;
    const int i = blockIdx.y * 8 + ((w & 1) << 2) + di;
    const int j = blockIdx.x * 8 + ((w >> 1) << 2) + dj;

    const RayCtx c = make_ray(quats, b, i, j);

    float acc = 0.0f;
    float kf = (float)dk - 128.0f;   // gk for k = 4t+dk; exact integer steps

#pragma unroll 8
    for (int t = 0; t < 64; ++t) {
        float px = fminf(fmaxf(fmaf(kf, c.dPx, c.bPx), 0.0f), 255.0f);
        float py = fminf(fmaxf(fmaf(kf, c.dPy, c.bPy), 0.0f), 255.0f);
        float pz = fminf(fmaxf(fmaf(kf, c.dPz, c.bPz), 0.0f), 255.0f);
        kf += 4.0f;

        const int x0 = (int)px;                 // trunc == floor (px >= 0)
        const int y0 = (int)py;
        const int z0 = (int)pz;
        const float tfx = __builtin_amdgcn_fractf(px);
        const float tfy = __builtin_amdgcn_fractf(py);
        const float tfz = __builtin_amdgcn_fractf(pz);
        const int dz16 = (z0 < NN - 1) ? (1 << 16) : 0;

        const int idx = (z0 << 16) | (y0 << 8) | x0;
        const uint2 A = v4[idx];
        const uint2 D = v4[idx + dz16];

        const float2 a0 = unpack2h(A.x);   // (z0,y0,x0), (z0,y0,x1)
        const float2 a1 = unpack2h(A.y);   // (z0,y1,x0), (z0,y1,x1)
        const float2 d0 = unpack2h(D.x);   // (z1,y0,*)
        const float2 d1 = unpack2h(D.y);   // (z1,y1,*)

        const float ux = 1.0f - tfx, uy = 1.0f - tfy, uz = 1.0f - tfz;
        const float c00 = a0.x * ux + a0.y * tfx;
        const float c01 = a1.x * ux + a1.y * tfx;
        const float c10 = d0.x * ux + d0.y * tfx;
        const float c11 = d1.x * ux + d1.y * tfx;
        const float c0 = c00 * uy + c01 * tfy;
        const float c1 = c10 * uy + c11 * tfy;
        acc += c0 * uz + c1 * tfz;
    }

    // fold the 4 k-residue partials (lanes differing in dk = bits 4,5)
    acc += __shfl_xor(acc, 16, 64);
    acc += __shfl_xor(acc, 32, 64);
    if (dk == 0) {
        out[(b << 16) | (i << 8) | j] = acc;
    }
}

// ---------------- direct fallback (round-2 proven path) ----------------

__global__ __launch_bounds__(256) void rotproj_direct_kernel(
    const float* __restrict__ vol,
    const float* __restrict__ quats,
    float* __restrict__ out)
{
    const int tx = threadIdx.x & 7;
    const int ty = (threadIdx.x >> 3) & 7;
    const int tz = threadIdx.x >> 6;
    const int b = blockIdx.z;
    const int i = blockIdx.y * 8 + ty;
    const int j = blockIdx.x * 8 + tx;

    const RayCtx c = make_ray(quats, b, i, j);

    float acc = 0.0f;
    float kf = (float)(tz * 64) - 128.0f;
#pragma unroll 4
    for (int kk = 0; kk < 64; ++kk) {
        float px = fminf(fmaxf(fmaf(kf, c.dPx, c.bPx), 0.0f), 255.0f);
        float py = fminf(fmaxf(fmaf(kf, c.dPy, c.bPy), 0.0f), 255.0f);
        float pz = fminf(fmaxf(fmaf(kf, c.dPz, c.bPz), 0.0f), 255.0f);
        kf += 1.0f;

        const int x0 = (int)px, y0 = (int)py, z0 = (int)pz;
        const float tfx = __builtin_amdgcn_fractf(px);
        const float tfy = __builtin_amdgcn_fractf(py);
        const float tfz = __builtin_amdgcn_fractf(pz);
        const int x1 = min(x0 + 1, NN - 1);
        const int y1 = min(y0 + 1, NN - 1);
        const int z1 = min(z0 + 1, NN - 1);

        const float* row00 = vol + ((z0 << 16) | (y0 << 8));
        const float* row01 = vol + ((z0 << 16) | (y1 << 8));
        const float* row10 = vol + ((z1 << 16) | (y0 << 8));
        const float* row11 = vol + ((z1 << 16) | (y1 << 8));

        const float v000 = row00[x0], v001 = row00[x1];
        const float v010 = row01[x0], v011 = row01[x1];
        const float v100 = row10[x0], v101 = row10[x1];
        const float v110 = row11[x0], v111 = row11[x1];

        const float ux = 1.0f - tfx, uy = 1.0f - tfy, uz = 1.0f - tfz;
        const float c00 = v000 * ux + v001 * tfx;
        const float c01 = v010 * ux + v011 * tfx;
        const float c10 = v100 * ux + v101 * tfx;
        const float c11 = v110 * ux + v111 * tfx;
        const float c0 = c00 * uy + c01 * tfy;
        const float c1 = c10 * uy + c11 * tfy;
        acc += c0 * uz + c1 * tfz;
    }

    __shared__ float sm[4][8][8];
    sm[tz][ty][tx] = acc;
    __syncthreads();
    if (tz == 0) {
        out[(b << 16) | (i << 8) | j] =
            sm[0][ty][tx] + sm[1][ty][tx] + sm[2][ty][tx] + sm[3][ty][tx];
    }
}

// ---------------- launch ----------------

extern "C" void kernel_launch(void* const* d_in, const int* in_sizes, int n_in,
                              void* d_out, int out_size, void* d_ws, size_t ws_size,
                              hipStream_t stream) {
    const float* vol = (const float*)d_in[0];
    const float* quats = (const float*)d_in[1];
    float* out = (float*)d_out;

    const int B = in_sizes[1] / 4;  // quaternions: (B,4)
    const size_t nvox = (size_t)NN * NN * NN;
    const size_t need = nvox * sizeof(uint2);   // 134 MB

    dim3 grid(NN / 8, NN / 8, B);
    dim3 block(256, 1, 1);

    if (ws_size >= need) {
        uint2* v4 = (uint2*)d_ws;
        hipLaunchKernelGGL(pack4h_kernel, dim3(NN * 16), dim3(256), 0, stream,
                           vol, v4);
        hipLaunchKernelGGL(rotproj4h_kernel, grid, block, 0, stream, v4, quats, out);
    } else {
        hipLaunchKernelGGL(rotproj_direct_kernel, grid, block, 0, stream,
                           vol, quats, out);
    }
}

// Round 11
// 247.685 us; speedup vs baseline: 1.3632x; 1.3632x over previous
//
#include <hip/hip_runtime.h>
#include <hip/hip_fp16.h>

// Volume rotate + trilinear resample + projection along axis 2.
// Round-11: fp16 4-corner pack -> 2 gathers/sample, 4x4x4 wave bricks,
// pixel-space fused ray constants (all proven), PLUS:
//   BRICKED PACK LAYOUT: granules stored in 8x8x8-voxel bricks (4 KB = 2
//   DRAM pages). A wave-gather's ~7^3 footprint hits ~8 bricks instead of
//   ~49 scattered rows -> HBM page locality. Plain stores (no nt) so L3
//   can retain. Pack content per granule unchanged (pure addr permutation).
//
// granule(z,y,x) = (V[z,y,x],V[z,y,x1],V[z,y1,x],V[z,y1,x1]) as 4xfp16, 8B.
// brick index: ((z>>3)<<19)|((y>>3)<<14)|((x>>3)<<9)|((z&7)<<6)|((y&7)<<3)|(x&7)

#define NN 256

typedef unsigned uv4 __attribute__((ext_vector_type(4)));

// ---------------- helpers ----------------

__device__ __forceinline__ unsigned pack2h(float lo, float hi) {
    __half2 h = __floats2half2_rn(lo, hi);
    return *reinterpret_cast<unsigned*>(&h);
}

__device__ __forceinline__ float2 unpack2h(unsigned u) {
    __half2 h = *reinterpret_cast<__half2*>(&u);
    return __half22float2(h);
}

// ---------------- pack kernel (brick-layout stores) ----------------

__global__ __launch_bounds__(256) void pack4hb_kernel(
    const float* __restrict__ vol, uint2* __restrict__ v4)
{
    const int t = blockIdx.x * 256 + threadIdx.x;   // [0, 2^24/4)
    const int x4 = (t & 63) << 2;                   // 0,4,...,252
    const int zy = t >> 6;                          // (z<<8)|y
    const int y = zy & 255;
    const int y1 = min(y + 1, NN - 1);
    const int z = zy >> 8;

    const float* r0 = vol + ((z << 16) | (y  << 8));
    const float* r1 = vol + ((z << 16) | (y1 << 8));
    const float4 p0 = *reinterpret_cast<const float4*>(r0 + x4);
    const float4 p1 = *reinterpret_cast<const float4*>(r1 + x4);
    const float n0 = (x4 == 252) ? p0.w : r0[x4 + 4];
    const float n1 = (x4 == 252) ? p1.w : r1[x4 + 4];

    uv4 lo, hi;
    lo.x = pack2h(p0.x, p0.y);  lo.y = pack2h(p1.x, p1.y);   // x4+0
    lo.z = pack2h(p0.y, p0.z);  lo.w = pack2h(p1.y, p1.z);   // x4+1
    hi.x = pack2h(p0.z, p0.w);  hi.y = pack2h(p1.z, p1.w);   // x4+2
    hi.z = pack2h(p0.w, n0);    hi.w = pack2h(p1.w, n1);     // x4+3

    // brick-layout destination; x4&7 in {0,4} so 4 granules are contiguous
    const int bidx = ((z >> 3) << 19) | ((y >> 3) << 14) | ((x4 >> 3) << 9)
                   | ((z & 7) << 6)  | ((y & 7) << 3)   | (x4 & 7);
    uv4* dst = reinterpret_cast<uv4*>(v4 + bidx);
    dst[0] = lo;
    dst[1] = hi;
}

// ---------------- geometry ----------------
// Pixel-space ray constants (continuity-safe; see round-8 derivation).

struct RayCtx {
    float bPx, bPy, bPz;    // pixel-space base
    float dPx, dPy, dPz;    // pixel-space k-direction
};

__device__ __forceinline__ RayCtx make_ray(const float* __restrict__ quats,
                                           int b, int i, int j)
{
    const float q0 = quats[b * 4 + 0];
    const float q1 = quats[b * 4 + 1];
    const float q2 = quats[b * 4 + 2];
    const float q3 = quats[b * 4 + 3];
    const float nrm = sqrtf(q0 * q0 + q1 * q1 + q2 * q2 + q3 * q3);
    const float qw = q0 / nrm, qx = q1 / nrm, qy = q2 / nrm, qz = q3 / nrm;

    const float r00 = 1.0f - 2.0f * (qy * qy + qz * qz);
    const float r01 = 2.0f * (qx * qy - qz * qw);
    const float r02 = 2.0f * (qx * qz + qy * qw);
    const float r10 = 2.0f * (qx * qy + qz * qw);
    const float r11 = 1.0f - 2.0f * (qx * qx + qz * qz);
    const float r12 = 2.0f * (qy * qz - qx * qw);
    const float r20 = 2.0f * (qx * qz - qy * qw);
    const float r21 = 2.0f * (qy * qz + qx * qw);
    const float r22 = 1.0f - 2.0f * (qx * qx + qy * qy);

    const float gi = (float)i - 128.0f;
    const float gj = (float)j - 128.0f;

    const float bx = gi * r00 + gj * r01;
    const float by = gi * r10 + gj * r11;
    const float bz = gi * r20 + gj * r21;

    const float K = 127.5f / 128.0f;   // exact fp32
    RayCtx c;
    c.dPx = r02 * K;  c.dPy = r12 * K;  c.dPz = r22 * K;
    c.bPx = bx * K + 127.5f;
    c.bPy = by * K + 127.5f;
    c.bPz = bz * K + 127.5f;
    return c;
}

// ---------------- main kernel: 4x4x4 lane bricks, 2 gathers/sample ----------

__global__ __launch_bounds__(256) void rotproj4hb_kernel(
    const uint2* __restrict__ v4,
    const float* __restrict__ quats,
    float* __restrict__ out)
{
    const int tid = threadIdx.x;
    const int w = tid >> 6;
    const int l = tid & 63;
    const int di = l & 3;
    const int dj = (l >> 2) & 3;
    const int dk = l >> 4;

    const int b = blockIdx.z;
    const int i = blockIdx.y * 8 + ((w & 1) << 2) + di;
    const int j = blockIdx.x * 8 + ((w >> 1) << 2) + dj;

    const RayCtx c = make_ray(quats, b, i, j);

    float acc = 0.0f;
    float kf = (float)dk - 128.0f;   // gk for k = 4t+dk; exact integer steps

#pragma unroll 8
    for (int t = 0; t < 64; ++t) {
        float px = fminf(fmaxf(fmaf(kf, c.dPx, c.bPx), 0.0f), 255.0f);
        float py = fminf(fmaxf(fmaf(kf, c.dPy, c.bPy), 0.0f), 255.0f);
        float pz = fminf(fmaxf(fmaf(kf, c.dPz, c.bPz), 0.0f), 255.0f);
        kf += 4.0f;

        const int x0 = (int)px;                 // trunc == floor (px >= 0)
        const int y0 = (int)py;
        const int z0 = (int)pz;
        const float tfx = __builtin_amdgcn_fractf(px);
        const float tfy = __builtin_amdgcn_fractf(py);
        const float tfz = __builtin_amdgcn_fractf(pz);
        const int z1 = z0 + (z0 < NN - 1 ? 1 : 0);

        // brick-layout addresses (y/x part shared between the two gathers)
        const int yx = ((y0 >> 3) << 14) | ((x0 >> 3) << 9)
                     | ((y0 & 7) << 3)  | (x0 & 7);
        const int za = ((z0 >> 3) << 19) | ((z0 & 7) << 6);
        const int zd = ((z1 >> 3) << 19) | ((z1 & 7) << 6);

        const uint2 A = v4[yx | za];
        const uint2 D = v4[yx | zd];

        const float2 a0 = unpack2h(A.x);   // (z0,y0,x0), (z0,y0,x1)
        const float2 a1 = unpack2h(A.y);   // (z0,y1,x0), (z0,y1,x1)
        const float2 d0 = unpack2h(D.x);   // (z1,y0,*)
        const float2 d1 = unpack2h(D.y);   // (z1,y1,*)

        const float ux = 1.0f - tfx, uy = 1.0f - tfy, uz = 1.0f - tfz;
        const float c00 = a0.x * ux + a0.y * tfx;
        const float c01 = a1.x * ux + a1.y * tfx;
        const float c10 = d0.x * ux + d0.y * tfx;
        const float c11 = d1.x * ux + d1.y * tfx;
        const float c0 = c00 * uy + c01 * tfy;
        const float c1 = c10 * uy + c11 * tfy;
        acc += c0 * uz + c1 * tfz;
    }

    // fold the 4 k-residue partials (lanes differing in dk = bits 4,5)
    acc += __shfl_xor(acc, 16, 64);
    acc += __shfl_xor(acc, 32, 64);
    if (dk == 0) {
        out[(b << 16) | (i << 8) | j] = acc;
    }
}

// ---------------- direct fallback (proven path) ----------------

__global__ __launch_bounds__(256) void rotproj_direct_kernel(
    const float* __restrict__ vol,
    const float* __restrict__ quats,
    float* __restrict__ out)
{
    const int tx = threadIdx.x & 7;
    const int ty = (threadIdx.x >> 3) & 7;
    const int tz = threadIdx.x >> 6;
    const int b = blockIdx.z;
    const int i = blockIdx.y * 8 + ty;
    const int j = blockIdx.x * 8 + tx;

    const RayCtx c = make_ray(quats, b, i, j);

    float acc = 0.0f;
    float kf = (float)(tz * 64) - 128.0f;
#pragma unroll 4
    for (int kk = 0; kk < 64; ++kk) {
        float px = fminf(fmaxf(fmaf(kf, c.dPx, c.bPx), 0.0f), 255.0f);
        float py = fminf(fmaxf(fmaf(kf, c.dPy, c.bPy), 0.0f), 255.0f);
        float pz = fminf(fmaxf(fmaf(kf, c.dPz, c.bPz), 0.0f), 255.0f);
        kf += 1.0f;

        const int x0 = (int)px, y0 = (int)py, z0 = (int)pz;
        const float tfx = __builtin_amdgcn_fractf(px);
        const float tfy = __builtin_amdgcn_fractf(py);
        const float tfz = __builtin_amdgcn_fractf(pz);
        const int x1 = min(x0 + 1, NN - 1);
        const int y1 = min(y0 + 1, NN - 1);
        const int z1 = min(z0 + 1, NN - 1);

        const float* row00 = vol + ((z0 << 16) | (y0 << 8));
        const float* row01 = vol + ((z0 << 16) | (y1 << 8));
        const float* row10 = vol + ((z1 << 16) | (y0 << 8));
        const float* row11 = vol + ((z1 << 16) | (y1 << 8));

        const float v000 = row00[x0], v001 = row00[x1];
        const float v010 = row01[x0], v011 = row01[x1];
        const float v100 = row10[x0], v101 = row10[x1];
        const float v110 = row11[x0], v111 = row11[x1];

        const float ux = 1.0f - tfx, uy = 1.0f - tfy, uz = 1.0f - tfz;
        const float c00 = v000 * ux + v001 * tfx;
        const float c01 = v010 * ux + v011 * tfx;
        const float c10 = v100 * ux + v101 * tfx;
        const float c11 = v110 * ux + v111 * tfx;
        const float c0 = c00 * uy + c01 * tfy;
        const float c1 = c10 * uy + c11 * tfy;
        acc += c0 * uz + c1 * tfz;
    }

    __shared__ float sm[4][8][8];
    sm[tz][ty][tx] = acc;
    __syncthreads();
    if (tz == 0) {
        out[(b << 16) | (i << 8) | j] =
            sm[0][ty][tx] + sm[1][ty][tx] + sm[2][ty][tx] + sm[3][ty][tx];
    }
}

// ---------------- launch ----------------

extern "C" void kernel_launch(void* const* d_in, const int* in_sizes, int n_in,
                              void* d_out, int out_size, void* d_ws, size_t ws_size,
                              hipStream_t stream) {
    const float* vol = (const float*)d_in[0];
    const float* quats = (const float*)d_in[1];
    float* out = (float*)d_out;

    const int B = in_sizes[1] / 4;  // quaternions: (B,4)
    const size_t nvox = (size_t)NN * NN * NN;
    const size_t need = nvox * sizeof(uint2);   // 134 MB

    dim3 grid(NN / 8, NN / 8, B);
    dim3 block(256, 1, 1);

    if (ws_size >= need) {
        uint2* v4 = (uint2*)d_ws;
        const int pack_blocks = (int)(nvox / 4 / 256);
        hipLaunchKernelGGL(pack4hb_kernel, dim3(pack_blocks), dim3(256), 0, stream,
                           vol, v4);
        hipLaunchKernelGGL(rotproj4hb_kernel, grid, block, 0, stream,
                           v4, quats, out);
    } else {
        hipLaunchKernelGGL(rotproj_direct_kernel, grid, block, 0, stream,
                           vol, quats, out);
    }
}